// Round 13
// baseline (326.349 us; speedup 1.0000x reference)
//
#include <hip/hip_runtime.h>
#include <math.h>

#define BATCH 16
#define NTOK  1024
#define NCLU  4096
#define DIM   768
#define MROWS (BATCH * NTOK)   // 16384

constexpr float TT_INV    = 16.666666666666668f;  // 1/0.06
constexpr float PT_INV    = 8.333333333333334f;   // 1/0.12
constexpr float SK_EPS_   = 1e-8f;
constexpr float NORM_EPS_ = 1e-7f;
constexpr float COL_SHIFT = 60.0f;   // logits ~ N(0,1): exp(L/T-60) never overflows
constexpr float P_SHIFT   = 40.0f;   // P = L/0.12 in (-60,60); exp(P-40) safe

typedef _Float16 f16x8 __attribute__((ext_vector_type(8)));
typedef _Float16 f16x4 __attribute__((ext_vector_type(4)));
typedef float    f32x4 __attribute__((ext_vector_type(4)));

// ---------------------------------------------------------------- helpers
struct F8 { float v[8]; };

__device__ __forceinline__ F8 load8(const float* p) {
    const float4 a = *(const float4*)p;
    const float4 b = *(const float4*)(p + 4);
    return F8{{a.x, a.y, a.z, a.w, b.x, b.y, b.z, b.w}};
}
__device__ __forceinline__ F8 load8(const _Float16* p) {
    f16x8 h = *(const f16x8*)p;
    F8 r;
#pragma unroll
    for (int i = 0; i < 8; ++i) r.v[i] = (float)h[i];
    return r;
}

__device__ __forceinline__ float wave_sum(float s) {
#pragma unroll
    for (int off = 32; off; off >>= 1) s += __shfl_xor(s, off);
    return s;
}

// async global->LDS, 16B per lane; LDS dest = wave-uniform base + lane*16
__device__ __forceinline__ void gl_lds16(const void* g, void* l) {
    __builtin_amdgcn_global_load_lds(
        (const __attribute__((address_space(1))) unsigned int*)g,
        (__attribute__((address_space(3))) unsigned int*)l,
        16, 0, 0);
}

// ------------------------------------------------------------- pre-casting
__global__ __launch_bounds__(256) void castx_kernel(
    const float* __restrict__ x, _Float16* __restrict__ x16)
{
    int row  = (blockIdx.x * 256 + threadIdx.x) >> 6;
    int lane = threadIdx.x & 63;
    const float4* rp = (const float4*)(x + (size_t)row * DIM);
    float4 v[3];
    float ss = 0.f;
#pragma unroll
    for (int i = 0; i < 3; ++i) {
        v[i] = rp[lane + i * 64];
        ss += v[i].x * v[i].x + v[i].y * v[i].y + v[i].z * v[i].z + v[i].w * v[i].w;
    }
    ss = wave_sum(ss);
    float sc = 1.0f / fmaxf(sqrtf(ss), NORM_EPS_);
    _Float16* op = x16 + (size_t)row * DIM;
#pragma unroll
    for (int i = 0; i < 3; ++i) {
        f16x4 h;
        h[0] = (_Float16)(v[i].x * sc); h[1] = (_Float16)(v[i].y * sc);
        h[2] = (_Float16)(v[i].z * sc); h[3] = (_Float16)(v[i].w * sc);
        *(f16x4*)(op + 4 * (lane + i * 64)) = h;
    }
}

__global__ __launch_bounds__(256) void castw_kernel(
    const float* __restrict__ w, _Float16* __restrict__ w16)
{
    int i = blockIdx.x * 256 + threadIdx.x;
    const float4 a = *(const float4*)(w + (size_t)i * 8);
    const float4 b = *(const float4*)(w + (size_t)i * 8 + 4);
    f16x8 h;
    h[0] = (_Float16)a.x; h[1] = (_Float16)a.y; h[2] = (_Float16)a.z; h[3] = (_Float16)a.w;
    h[4] = (_Float16)b.x; h[5] = (_Float16)b.y; h[6] = (_Float16)b.z; h[7] = (_Float16)b.w;
    *(f16x8*)(w16 + (size_t)i * 8) = h;
}

// ---------------------------------------------------------------- row norms (tier 2/3)
__global__ __launch_bounds__(256) void rownorm_kernel(
    const float* __restrict__ x, float* __restrict__ invn)
{
    int wave = (blockIdx.x * 256 + threadIdx.x) >> 6;
    int lane = threadIdx.x & 63;
    const float4* row = (const float4*)(x + (size_t)wave * DIM);
    float s = 0.f;
#pragma unroll
    for (int i = 0; i < 3; ++i) {
        float4 v = row[lane + i * 64];
        s += v.x * v.x + v.y * v.y + v.z * v.z + v.w * v.w;
    }
    s = wave_sum(s);
    if (lane == 0) invn[wave] = 1.0f / fmaxf(sqrtf(s), NORM_EPS_);
}

// ================================================================ fast GEMM
// 256x256 tile, 8 waves (2M x 4N, per-wave 128x64). Phases over K-halves of
// 32: 24 phases, 2-slab LDS ring (64 KB -> 2 blocks/CU for cross-block
// latency hiding), stage 1 slab ahead, counted vmcnt(4) + 2 barriers per
// phase. T5: setprio(1) around MFMA cluster. Epilogue: full-line C stores +
// fused colpass1 partials.
#define GKH   32              // K per phase
#define NKH   (DIM / GKH)     // 24 phases

__global__ void __launch_bounds__(512, 1) gemm16(
    const _Float16* __restrict__ A,   // x16 [MROWS][DIM]
    const _Float16* __restrict__ B,   // w16 [NCLU][DIM]
    const float* __restrict__ bias,
    _Float16* __restrict__ out,
    float* __restrict__ colpart)      // [64 rowblocks][NCLU]
{
    __shared__ __align__(16) _Float16 AS[2][8192];  // 2 x 16 KB
    __shared__ __align__(16) _Float16 BS[2][8192];  // 2 x 16 KB

    const int tid  = threadIdx.x;
    const int lane = tid & 63;
    const int wid  = tid >> 6;          // 0..7
    const int wm   = wid >> 2;          // 0..1  (M)
    const int wn   = wid & 3;           // 0..3  (N)

    // bijective XCD-aware swizzle (nwg = 1024, %8 == 0)
    const int nwg = gridDim.x;
    const int cpx = nwg >> 3;
    const int swz = (blockIdx.x & 7) * cpx + (blockIdx.x >> 3);
    const int brow = (swz >> 4) * 256;   // 64 row-blocks
    const int bcol = (swz & 15) * 256;   // 16 col-blocks

    // ---- staging decode: LDS granule G (16B) holds (pairrow pr=G>>3, slot s=G&7)
    // with content row r = 2*pr + (s>>2), k-chunk q = (s&3) ^ (pr&3).
    const int G0 = tid, G1 = tid + 512;
    const int pr0 = G0 >> 3, s0 = G0 & 7;
    const int rr0 = pr0 * 2 + (s0 >> 2), qq0 = (s0 & 3) ^ (pr0 & 3);
    const int pr1 = G1 >> 3, s1 = G1 & 7;
    const int rr1 = pr1 * 2 + (s1 >> 2), qq1 = (s1 & 3) ^ (pr1 & 3);

    const _Float16* sA0 = A + (size_t)(brow + rr0) * DIM + qq0 * 8;
    const _Float16* sA1 = A + (size_t)(brow + rr1) * DIM + qq1 * 8;
    const _Float16* sB0 = B + (size_t)(bcol + rr0) * DIM + qq0 * 8;
    const _Float16* sB1 = B + (size_t)(bcol + rr1) * DIM + qq1 * 8;
    const int ldsOff0 = wid * 512;          // f16 units; lane adds 16B via HW
    const int ldsOff1 = wid * 512 + 4096;

    // ---- fragment read geometry (16x16x32: lane=(q,fr), k=q*8..+8)
    const int q  = lane >> 4;
    const int fr = lane & 15;
    const int qp = q ^ ((fr >> 1) & 3);                    // XOR involution
    const int fbase = ((fr & 1) * 4 + qp) * 8;
    const int abase = (wm * 64 + (fr >> 1)) * 64 + fbase;  // m stride: 512
    const int bbase = (wn * 32 + (fr >> 1)) * 64 + fbase;  // n stride: 512

    f32x4 acc[8][4] = {};

#define STAGE4(slot, kh) {                                  \
    const int ko_ = (kh) * GKH;                             \
    gl_lds16(sA0 + ko_, &AS[slot][ldsOff0]);                \
    gl_lds16(sA1 + ko_, &AS[slot][ldsOff1]);                \
    gl_lds16(sB0 + ko_, &BS[slot][ldsOff0]);                \
    gl_lds16(sB1 + ko_, &BS[slot][ldsOff1]); }

#define PHASE(slotC, slotS, khS) {                                         \
    STAGE4(slotS, khS);                                                    \
    asm volatile("s_waitcnt vmcnt(4)" ::: "memory");                       \
    __builtin_amdgcn_s_barrier();                                          \
    asm volatile("" ::: "memory");                                         \
    f16x8 af[8], bf[4];                                                    \
    _Pragma("unroll")                                                      \
    for (int m = 0; m < 8; ++m)                                            \
        af[m] = *(const f16x8*)&AS[slotC][abase + m * 512];                \
    _Pragma("unroll")                                                      \
    for (int n = 0; n < 4; ++n)                                            \
        bf[n] = *(const f16x8*)&BS[slotC][bbase + n * 512];                \
    __builtin_amdgcn_s_setprio(1);                                         \
    _Pragma("unroll")                                                      \
    for (int m = 0; m < 8; ++m)                                            \
        _Pragma("unroll")                                                  \
        for (int n = 0; n < 4; ++n)                                        \
            acc[m][n] = __builtin_amdgcn_mfma_f32_16x16x32_f16(            \
                af[m], bf[n], acc[m][n], 0, 0, 0);                         \
    __builtin_amdgcn_s_setprio(0);                                         \
    __builtin_amdgcn_s_barrier();   /* slot slotC reusable */              \
    asm volatile("" ::: "memory"); }

    // prologue: k-half 0 into slot 0  (4 loads outstanding)
    STAGE4(0, 0);

    for (int it = 0; it < NKH / 2; ++it) {   // 12 x 2 = 24 phases
        const int t0 = it * 2;
        const int kh1 = t0 + 1;
        const int kh2 = (t0 + 2 < NKH) ? t0 + 2 : 0;   // last stage = dummy
        PHASE(0, 1, kh1);
        PHASE(1, 0, kh2);
    }
#undef PHASE
#undef STAGE4

    __syncthreads();                       // drain all loads; LDS reusable

    // epilogue: full-line C writes (n innermost: 4 stores fill one 128B line
    // per row-quadrant) + fused colpass1 partial sums.
    // C/D layout: col=lane&15, row=(lane>>4)*4+j
    float cs[4] = {0.f, 0.f, 0.f, 0.f};
    float bv[4];
#pragma unroll
    for (int n = 0; n < 4; ++n) bv[n] = bias[bcol + wn * 64 + n * 16 + fr];
#pragma unroll
    for (int m = 0; m < 8; ++m) {
        int row0 = brow + wm * 128 + m * 16 + (q << 2);
#pragma unroll
        for (int j = 0; j < 4; ++j) {
            size_t ro = (size_t)(row0 + j) * NCLU + bcol + wn * 64 + fr;
#pragma unroll
            for (int n = 0; n < 4; ++n) {
                float v = acc[m][n][j] + bv[n];
                out[ro + n * 16] = (_Float16)v;
                cs[n] += __expf(v * TT_INV - COL_SHIFT);
            }
        }
    }
    float cred_local[4];
#pragma unroll
    for (int n = 0; n < 4; ++n) {
        float c2 = cs[n];
        c2 += __shfl_xor(c2, 16);
        c2 += __shfl_xor(c2, 32);          // sum over q -> wave's 128 rows
        cred_local[n] = c2;
    }
    float* cred = (float*)&AS[0][0];       // [wm][wn][n][fr] = 512 f32
#pragma unroll
    for (int n = 0; n < 4; ++n)
        if (q == 0) cred[((wm * 4 + wn) * 4 + n) * 16 + fr] = cred_local[n];
    __syncthreads();
    if (tid < 256) {
        int wn2 = tid >> 6, n2 = (tid >> 4) & 3, fr2 = tid & 15;
        float S = cred[((0 * 4 + wn2) * 4 + n2) * 16 + fr2]
                + cred[((1 * 4 + wn2) * 4 + n2) * 16 + fr2];
        colpart[(size_t)(swz >> 4) * NCLU + bcol + wn2 * 64 + n2 * 16 + fr2] = S;
    }
}

// colfin1: a1[b,k] = -COL_SHIFT - ln( sum_rb colpart[b*4+rb][k] )   (exact, no eps)
__global__ __launch_bounds__(256) void colfin_kernel(
    const float* __restrict__ part, float* __restrict__ a1)
{
    int i = blockIdx.x * 256 + threadIdx.x;   // 65536
    int b = i >> 12, k = i & (NCLU - 1);
    const float* p = part + (size_t)(b * 4) * NCLU + k;
    float s = 0.f;
#pragma unroll
    for (int rb = 0; rb < 4; ++rb) { s += *p; p += NCLU; }
    a1[i] = -COL_SHIFT - __logf(s);
}

// ============================================ fused row+col Sinkhorn pass
// LDS-staged variant: 512 threads; phase 1 stages the 16x4096 f16 chunk into
// LDS while computing row sums; phase 2 reads LDS instead of re-reading global.
template <bool FIRST>
__global__ void __launch_bounds__(512, 1) rcpassL_kernel(
    const _Float16* __restrict__ L, const float* __restrict__ a_in,
    const float* __restrict__ b_in, float* __restrict__ b_out,
    float* __restrict__ part)         // [1024][NCLU]
{
    __shared__ __align__(16) _Float16 Lsh[16][NCLU];   // 128 KB
    __shared__ float wgt_sh[16];
    const int tid  = threadIdx.x;          // 0..511
    const int lane = tid & 63;
    const int wv   = tid >> 6;             // 0..7
    const int chunk = blockIdx.x;          // 0..1023
    const int b     = chunk >> 6;          // batch
    const int row0  = chunk * 16;
    const float* av = a_in + (size_t)b * NCLU;

    float ar[8][8];
#pragma unroll
    for (int i = 0; i < 8; ++i) {
        int c = i * 64 + lane;
        *(float4*)&ar[i][0] = *(const float4*)&av[c * 8];
        *(float4*)&ar[i][4] = *(const float4*)&av[c * 8 + 4];
    }

#pragma unroll
    for (int rr = 0; rr < 2; ++rr) {
        int lr  = wv * 2 + rr;
        int row = row0 + lr;
        const _Float16* Lr = L + (size_t)row * NCLU;
        float bp = FIRST ? 0.f : b_in[row];
        float s = 0.f;
#pragma unroll
        for (int i = 0; i < 8; ++i) {
            int c = i * 64 + lane;
            f16x8 h = *(const f16x8*)&Lr[c * 8];
            *(f16x8*)&Lsh[lr][c * 8] = h;
#pragma unroll
            for (int j = 0; j < 8; ++j)
                s += __expf((float)h[j] * TT_INV + ar[i][j] + bp);
        }
        s = wave_sum(s);
        if (lane == 0) {
            float bn = bp - __logf(s + SK_EPS_);
            b_out[row] = bn;
            wgt_sh[lr] = __expf(bn);
        }
    }
    __syncthreads();

    float aown[8];
    *(float4*)&aown[0] = *(const float4*)&av[tid * 8];
    *(float4*)&aown[4] = *(const float4*)&av[tid * 8 + 4];
    float acc[8] = {};
    for (int rr = 0; rr < 16; ++rr) {
        f16x8 h = *(const f16x8*)&Lsh[rr][tid * 8];
        float wg = wgt_sh[rr];
#pragma unroll
        for (int j = 0; j < 8; ++j)
            acc[j] += __expf((float)h[j] * TT_INV + aown[j]) * wg;
    }
    float* P = part + (size_t)chunk * NCLU;
    f32x4 w0, w1;
    w0[0] = acc[0]; w0[1] = acc[1]; w0[2] = acc[2]; w0[3] = acc[3];
    w1[0] = acc[4]; w1[1] = acc[5]; w1[2] = acc[6]; w1[3] = acc[7];
    *(f32x4*)&P[tid * 8]     = w0;
    *(f32x4*)&P[tid * 8 + 4] = w1;
}

// colfinN: a_out[b,k] = a_in[b,k] - ln( sum_{c in batch's 64 chunks} part[c][k] + eps )
__global__ __launch_bounds__(256) void colfinN_kernel(
    const float* __restrict__ part, const float* __restrict__ a_in,
    float* __restrict__ a_out)
{
    int i = blockIdx.x * 256 + threadIdx.x;   // 65536
    int b = i >> 12, k = i & (NCLU - 1);
    const float* p = part + (size_t)(b * 64) * NCLU + k;
    float s = 0.f;
#pragma unroll 8
    for (int c = 0; c < 64; ++c) { s += *p; p += NCLU; }
    a_out[i] = a_in[i] - __logf(s + SK_EPS_);
}

// ------------------------------------------------- tier-2/3 GEMM (convert in-kernel)
#define BM 128
#define BN 128
#define BKF 32
#define LDK 40

__device__ __forceinline__ f16x8 pack8(float4 lo, float4 hi, float sc) {
    f16x8 h;
    h[0] = (_Float16)(lo.x * sc); h[1] = (_Float16)(lo.y * sc);
    h[2] = (_Float16)(lo.z * sc); h[3] = (_Float16)(lo.w * sc);
    h[4] = (_Float16)(hi.x * sc); h[5] = (_Float16)(hi.y * sc);
    h[6] = (_Float16)(hi.z * sc); h[7] = (_Float16)(hi.w * sc);
    return h;
}

template <typename OT>
__global__ __launch_bounds__(256) void gemm_f16(
    const float* __restrict__ x, const float* __restrict__ w,
    const float* __restrict__ bias, const float* __restrict__ invn,
    OT* __restrict__ out)
{
    __shared__ __align__(16) _Float16 As[BM * LDK];
    __shared__ __align__(16) _Float16 Bs[BN * LDK];

    const int tid  = threadIdx.x;
    const int lane = tid & 63;
    const int wid  = tid >> 6;
    const int wr = wid >> 1, wc = wid & 1;
    const int brow = blockIdx.y * BM;
    const int bcol = blockIdx.x * BN;

    const int r0 = tid >> 2;
    const int r1 = r0 + 64;
    const int kc = (tid & 3) * 8;
    const float sA0 = invn[brow + r0];
    const float sA1 = invn[brow + r1];
    const float* gA0 = x + (size_t)(brow + r0) * DIM + kc;
    const float* gA1 = x + (size_t)(brow + r1) * DIM + kc;
    const float* gB0 = w + (size_t)(bcol + r0) * DIM + kc;
    const float* gB1 = w + (size_t)(bcol + r1) * DIM + kc;

    f32x4 acc[4][4] = {};
    float4 a00, a01, a10, a11, b00, b01, b10, b11;
    a00 = *(const float4*)(gA0);     a01 = *(const float4*)(gA0 + 4);
    a10 = *(const float4*)(gA1);     a11 = *(const float4*)(gA1 + 4);
    b00 = *(const float4*)(gB0);     b01 = *(const float4*)(gB0 + 4);
    b10 = *(const float4*)(gB1);     b11 = *(const float4*)(gB1 + 4);

    const int NT = DIM / BKF;
    for (int kt = 0; kt < NT; ++kt) {
        __syncthreads();
        *(f16x8*)&As[r0 * LDK + kc] = pack8(a00, a01, sA0);
        *(f16x8*)&As[r1 * LDK + kc] = pack8(a10, a11, sA1);
        *(f16x8*)&Bs[r0 * LDK + kc] = pack8(b00, b01, 1.0f);
        *(f16x8*)&Bs[r1 * LDK + kc] = pack8(b10, b11, 1.0f);
        __syncthreads();

        if (kt + 1 < NT) {
            int k0 = (kt + 1) * BKF;
            a00 = *(const float4*)(gA0 + k0); a01 = *(const float4*)(gA0 + k0 + 4);
            a10 = *(const float4*)(gA1 + k0); a11 = *(const float4*)(gA1 + k0 + 4);
            b00 = *(const float4*)(gB0 + k0); b01 = *(const float4*)(gB0 + k0 + 4);
            b10 = *(const float4*)(gB1 + k0); b11 = *(const float4*)(gB1 + k0 + 4);
        }

        const int ko = (lane >> 4) * 8;
        f16x8 af[4], bf[4];
#pragma unroll
        for (int m = 0; m < 4; ++m)
            af[m] = *(const f16x8*)&As[(wr * 64 + m * 16 + (lane & 15)) * LDK + ko];
#pragma unroll
        for (int n = 0; n < 4; ++n)
            bf[n] = *(const f16x8*)&Bs[(wc * 64 + n * 16 + (lane & 15)) * LDK + ko];
#pragma unroll
        for (int m = 0; m < 4; ++m)
#pragma unroll
            for (int n = 0; n < 4; ++n)
                acc[m][n] = __builtin_amdgcn_mfma_f32_16x16x32_f16(
                    af[m], bf[n], acc[m][n], 0, 0, 0);
    }

#pragma unroll
    for (int n = 0; n < 4; ++n) {
        int col = bcol + wc * 64 + n * 16 + (lane & 15);
        float bv = bias[col];
#pragma unroll
        for (int m = 0; m < 4; ++m) {
            int row0 = brow + wr * 64 + m * 16 + ((lane >> 4) << 2);
#pragma unroll
            for (int j = 0; j < 4; ++j)
                out[(size_t)(row0 + j) * NCLU + col] = (OT)(acc[m][n][j] + bv);
        }
    }
}

// ------------------------------------------------------------ column passes (tier 2/3)
template <typename T>
__global__ __launch_bounds__(256) void colpass_kernel(
    const T* __restrict__ L, const float* __restrict__ a_in,
    const float* __restrict__ b_in, float* __restrict__ a_out)
{
    __shared__ float bsh[NTOK];
    __shared__ float ss[4][64];
    int b = blockIdx.x >> 6;
    int k = ((blockIdx.x & 63) << 6) + (threadIdx.x & 63);
    int wv = threadIdx.x >> 6;
    int lane = threadIdx.x & 63;
    const bool first = (b_in == nullptr);
    if (first) {
        for (int i = threadIdx.x; i < NTOK; i += 256) bsh[i] = 0.f;
    } else {
        for (int i = threadIdx.x; i < NTOK; i += 256) bsh[i] = b_in[b * NTOK + i];
    }
    __syncthreads();
    float aval = first ? -COL_SHIFT : a_in[b * NCLU + k];
    const T* p = L + (size_t)b * NTOK * NCLU + (size_t)(wv * 256) * NCLU + k;
    float s = 0.f;
#pragma unroll 4
    for (int n = 0; n < 256; ++n) {
        s += __expf((float)(*p) * TT_INV + aval + bsh[wv * 256 + n]);
        p += NCLU;
    }
    ss[wv][lane] = s;
    __syncthreads();
    if (wv == 0) {
        float S = ss[0][lane] + ss[1][lane] + ss[2][lane] + ss[3][lane];
        a_out[b * NCLU + k] = aval - __logf(first ? S : S + SK_EPS_);
    }
}

template <typename T>
__global__ __launch_bounds__(256) void colpassV_kernel(
    const T* __restrict__ L, const float* __restrict__ a_in,
    const float* __restrict__ b_in, float* __restrict__ a_out)
{
    __shared__ float bsh[NTOK];
    __shared__ float red[16][16][8];   // 8 KB
    const int b     = blockIdx.x >> 5;
    const int strip = blockIdx.x & 31;
    const int cc    = threadIdx.x & 15;
    const int rg    = threadIdx.x >> 4;
    const int col0  = strip * 128 + cc * 8;
    for (int i = threadIdx.x; i < NTOK; i += 256) bsh[i] = b_in[b * NTOK + i];
    __syncthreads();
    const float4 av0 = *(const float4*)(a_in + b * NCLU + col0);
    const float4 av1 = *(const float4*)(a_in + b * NCLU + col0 + 4);
    const float av[8] = {av0.x, av0.y, av0.z, av0.w, av1.x, av1.y, av1.z, av1.w};
    float s[8] = {};
    const T* p = L + (size_t)b * NTOK * NCLU + (size_t)rg * NCLU + col0;
    for (int it = 0; it < 64; ++it) {
        F8 Lv = load8(p);
        float bpv = bsh[it * 16 + rg];
#pragma unroll
        for (int j = 0; j < 8; ++j) s[j] += __expf(Lv.v[j] * TT_INV + av[j] + bpv);
        p += (size_t)16 * NCLU;
    }
#pragma unroll
    for (int j = 0; j < 8; ++j) red[rg][cc][j] = s[j];
    __syncthreads();
    if (threadIdx.x < 128) {
        int c2 = threadIdx.x >> 3, j2 = threadIdx.x & 7;
        float S = 0.f;
#pragma unroll
        for (int g = 0; g < 16; ++g) S += red[g][c2][j2];
        int col = strip * 128 + c2 * 8 + j2;
        a_out[b * NCLU + col] = a_in[b * NCLU + col] - __logf(S + SK_EPS_);
    }
}

// ------------------------------------------------------------- row passes (tier 2/3)
template <typename T>
__global__ __launch_bounds__(256) void rowpass_kernel(
    const T* __restrict__ L, const float* __restrict__ a_in,
    const float* __restrict__ b_in, float* __restrict__ b_out)
{
    int row  = (blockIdx.x * 256 + threadIdx.x) >> 6;
    int lane = threadIdx.x & 63;
    int b = row >> 10;
    const T* Lr = L + (size_t)row * NCLU;
    const float* av = a_in + (size_t)b * NCLU;
    float bp = b_in ? b_in[row] : 0.f;
    float s = 0.f;
#pragma unroll
    for (int i = 0; i < 8; ++i) {
        int c = i * 64 + lane;
        F8 Lv = load8(Lr + c * 8);
        F8 Av = load8(av + c * 8);
#pragma unroll
        for (int j = 0; j < 8; ++j)
            s += __expf(Lv.v[j] * TT_INV + Av.v[j] + bp);
    }
    s = wave_sum(s);
    if (lane == 0) b_out[row] = bp - __logf(s + SK_EPS_);
}

// ---------------- final: assignments + per-row loss (single pass over L)
template <typename T>
__global__ __launch_bounds__(256) void final_kernel(
    const T* __restrict__ L, const float* __restrict__ a3,
    const float* __restrict__ b2, float* __restrict__ out,
    float* __restrict__ rowloss)
{
    __shared__ float red[3][4];
    const int row  = blockIdx.x;
    const int tid  = threadIdx.x;
    const int lane = tid & 63;
    const int wv   = tid >> 6;
    const int b    = row >> 10;
    const T* Lr = L + (size_t)row * NCLU;
    const float* av = a3 + (size_t)b * NCLU;
    const float bp = b2[row];

    float e[2][8];
    float rs = 0.f, q = 0.f, sP = 0.f;
#pragma unroll
    for (int jj = 0; jj < 2; ++jj) {
        int c = tid + jj * 256;
        F8 Lv = load8(Lr + c * 8);
        F8 Av = load8(av + c * 8);
#pragma unroll
        for (int j = 0; j < 8; ++j) {
            float P  = Lv.v[j] * PT_INV;
            float ev = __expf(Lv.v[j] * TT_INV + Av.v[j] + bp);
            e[jj][j] = ev;
            rs += ev;
            q  += ev * P;
            sP += __expf(P - P_SHIFT);
        }
    }
    rs = wave_sum(rs); q = wave_sum(q); sP = wave_sum(sP);
    if (lane == 0) { red[0][wv] = rs; red[1][wv] = q; red[2][wv] = sP; }
    __syncthreads();
    rs = red[0][0] + red[0][1] + red[0][2] + red[0][3];
    q  = red[1][0] + red[1][1] + red[1][2] + red[1][3];
    sP = red[2][0] + red[2][1] + red[2][2] + red[2][3];

    const float inv = 1.0f / (rs + SK_EPS_);
    const float lse = P_SHIFT + __logf(sP);

    float* Or = out + (size_t)row * NCLU;
#pragma unroll
    for (int jj = 0; jj < 2; ++jj) {
        int c = tid + jj * 256;
        f32x4 w0, w1;
        w0[0] = e[jj][0] * inv; w0[1] = e[jj][1] * inv;
        w0[2] = e[jj][2] * inv; w0[3] = e[jj][3] * inv;
        w1[0] = e[jj][4] * inv; w1[1] = e[jj][5] * inv;
        w1[2] = e[jj][6] * inv; w1[3] = e[jj][7] * inv;
        __builtin_nontemporal_store(w0, (f32x4*)(Or + c * 8));
        __builtin_nontemporal_store(w1, (f32x4*)(Or + c * 8 + 4));
    }
    if (tid == 0) rowloss[row] = q * inv - lse * (rs * inv);
}

// ------------------------------------------------------------- loss reduce
__global__ __launch_bounds__(256) void lossred_kernel(
    const float* __restrict__ rowloss, float* __restrict__ out_loss)
{
    __shared__ float red[4];
    int tid = threadIdx.x, lane = tid & 63, wv = tid >> 6;
    float s = 0.f;
    for (int i = tid; i < MROWS; i += 256) s += rowloss[i];
    s = wave_sum(s);
    if (lane == 0) red[wv] = s;
    __syncthreads();
    if (tid == 0)
        out_loss[0] = -(red[0] + red[1] + red[2] + red[3]) / (float)MROWS;
}

// ------------------------------------------------------------------ launch
extern "C" void kernel_launch(void* const* d_in, const int* in_sizes, int n_in,
                              void* d_out, int out_size, void* d_ws, size_t ws_size,
                              hipStream_t stream)
{
    const float* x    = (const float*)d_in[0];
    const float* w    = (const float*)d_in[1];
    const float* bias = (const float*)d_in[2];
    float* out = (float*)d_out;
    char* base = (char*)d_ws;
    float* ws  = (float*)d_ws;   // small region: a1..a3, b1, b2, rowloss (<1 MiB)

    float* a1      = ws;
    float* a2      = a1 + BATCH * NCLU;
    float* a3      = a2 + BATCH * NCLU;
    float* b1      = a3 + BATCH * NCLU;
    float* b2      = b1 + MROWS;
    float* rowloss = b2 + MROWS;

    const size_t SMALL = 1u << 20;
    const size_t L16B  = (size_t)MROWS * NCLU * 2;   // 128 MiB
    const size_t X16B  = (size_t)MROWS * DIM * 2;    // 24 MiB
    const size_t W16B  = (size_t)NCLU * DIM * 2;     // 6 MiB
    const size_t PARTB = (size_t)64 * NCLU * 4;      // 1 MiB

    const int CB = BATCH * (NCLU / 64);  // 1024
    const int RB = MROWS / 4;            // 4096

    if (ws_size >= SMALL + L16B + X16B + W16B + PARTB) {
        // tier 1: precast fp16 + 256^2 phase-pipelined GEMM + fused passes
        _Float16* L16 = (_Float16*)(base + SMALL);
        _Float16* X16 = (_Float16*)(base + SMALL + L16B);
        _Float16* W16 = (_Float16*)(base + SMALL + L16B + X16B);
        float*    part1 = (float*)(base + SMALL + L16B + X16B + W16B);
        // part (16 MiB) overlays X16 (24 MiB): X16 is dead after gemm16.
        float*    part  = (float*)(base + SMALL + L16B);

        castx_kernel<<<MROWS / 4, 256, 0, stream>>>(x, X16);
        castw_kernel<<<(NCLU * DIM / 8) / 256, 256, 0, stream>>>(w, W16);
        gemm16<<<(MROWS / 256) * (NCLU / 256), 512, 0, stream>>>(X16, W16, bias, L16, part1);
        colfin_kernel<<<BATCH * NCLU / 256, 256, 0, stream>>>(part1, a1);
        rcpassL_kernel<true ><<<MROWS / 16, 512, 0, stream>>>(L16, a1, nullptr, b1, part);
        colfinN_kernel<<<BATCH * NCLU / 256, 256, 0, stream>>>(part, a1, a2);
        rcpassL_kernel<false><<<MROWS / 16, 512, 0, stream>>>(L16, a2, b1, b2, part);
        colfinN_kernel<<<BATCH * NCLU / 256, 256, 0, stream>>>(part, a2, a3);
        final_kernel<_Float16><<<MROWS, 256, 0, stream>>>(L16, a3, b2, out, rowloss);
        lossred_kernel<<<1, 256, 0, stream>>>(rowloss, out + (size_t)MROWS * NCLU);
    } else if (ws_size >= SMALL + L16B) {
        // tier 2: fp16 logits in ws, convert inside GEMM
        float* invn = rowloss + MROWS;
        _Float16* L16 = (_Float16*)(base + SMALL);
        rownorm_kernel<<<MROWS / 4, 256, 0, stream>>>(x, invn);
        dim3 gg(NCLU / BN, MROWS / BM);
        gemm_f16<_Float16><<<gg, 256, 0, stream>>>(x, w, bias, invn, L16);
        colpass_kernel<_Float16><<<CB, 256, 0, stream>>>(L16, nullptr, nullptr, a1);
        rowpass_kernel<_Float16><<<RB, 256, 0, stream>>>(L16, a1, nullptr, b1);
        colpassV_kernel<_Float16><<<BATCH * 32, 256, 0, stream>>>(L16, a1, b1, a2);
        rowpass_kernel<_Float16><<<RB, 256, 0, stream>>>(L16, a2, b1, b2);
        colpassV_kernel<_Float16><<<BATCH * 32, 256, 0, stream>>>(L16, a2, b2, a3);
        final_kernel<_Float16><<<MROWS, 256, 0, stream>>>(L16, a3, b2, out, rowloss);
        lossred_kernel<<<1, 256, 0, stream>>>(rowloss, out + (size_t)MROWS * NCLU);
    } else {
        // tier 3: f32 logits in d_out
        float* invn = rowloss + MROWS;
        rownorm_kernel<<<MROWS / 4, 256, 0, stream>>>(x, invn);
        dim3 gg(NCLU / BN, MROWS / BM);
        gemm_f16<float><<<gg, 256, 0, stream>>>(x, w, bias, invn, out);
        colpass_kernel<float><<<CB, 256, 0, stream>>>(out, nullptr, nullptr, a1);
        rowpass_kernel<float><<<RB, 256, 0, stream>>>(out, a1, nullptr, b1);
        colpassV_kernel<float><<<BATCH * 32, 256, 0, stream>>>(out, a1, b1, a2);
        rowpass_kernel<float><<<RB, 256, 0, stream>>>(out, a2, b1, b2);
        colpassV_kernel<float><<<BATCH * 32, 256, 0, stream>>>(out, a2, b2, a3);
        final_kernel<float><<<MROWS, 256, 0, stream>>>(out, a3, b2, out, rowloss);
        lossred_kernel<<<1, 256, 0, stream>>>(rowloss, out + (size_t)MROWS * NCLU);
    }
}

// Round 14
// 317.458 us; speedup vs baseline: 1.0280x; 1.0280x over previous
//
#include <hip/hip_runtime.h>
#include <math.h>

#define BATCH 16
#define NTOK  1024
#define NCLU  4096
#define DIM   768
#define MROWS (BATCH * NTOK)   // 16384

constexpr float TT_INV    = 16.666666666666668f;  // 1/0.06
constexpr float PT_INV    = 8.333333333333334f;   // 1/0.12
constexpr float SK_EPS_   = 1e-8f;
constexpr float NORM_EPS_ = 1e-7f;
constexpr float COL_SHIFT = 60.0f;   // logits ~ N(0,1): exp(L/T-60) never overflows
constexpr float P_SHIFT   = 40.0f;   // P = L/0.12 in (-60,60); exp(P-40) safe

typedef _Float16 f16x8 __attribute__((ext_vector_type(8)));
typedef _Float16 f16x4 __attribute__((ext_vector_type(4)));
typedef float    f32x4 __attribute__((ext_vector_type(4)));

// ---------------------------------------------------------------- helpers
struct F8 { float v[8]; };

__device__ __forceinline__ F8 load8(const float* p) {
    const float4 a = *(const float4*)p;
    const float4 b = *(const float4*)(p + 4);
    return F8{{a.x, a.y, a.z, a.w, b.x, b.y, b.z, b.w}};
}
__device__ __forceinline__ F8 load8(const _Float16* p) {
    f16x8 h = *(const f16x8*)p;
    F8 r;
#pragma unroll
    for (int i = 0; i < 8; ++i) r.v[i] = (float)h[i];
    return r;
}

__device__ __forceinline__ float wave_sum(float s) {
#pragma unroll
    for (int off = 32; off; off >>= 1) s += __shfl_xor(s, off);
    return s;
}

// async global->LDS, 16B per lane; LDS dest = wave-uniform base + lane*16
__device__ __forceinline__ void gl_lds16(const void* g, void* l) {
    __builtin_amdgcn_global_load_lds(
        (const __attribute__((address_space(1))) unsigned int*)g,
        (__attribute__((address_space(3))) unsigned int*)l,
        16, 0, 0);
}

// ------------------------------------------------- merged pre-cast (x + w)
// blocks [0, 4096): normalize+cast x rows (4 rows/block, 1 wave each)
// blocks [4096, 5632): cast w (2048 elems/block)
#define XBLOCKS (MROWS / 4)                    // 4096
#define WBLOCKS ((NCLU * DIM / 8) / 256)       // 1536

__global__ __launch_bounds__(256) void castxw_kernel(
    const float* __restrict__ x, const float* __restrict__ w,
    _Float16* __restrict__ x16, _Float16* __restrict__ w16)
{
    if (blockIdx.x < XBLOCKS) {
        int row  = (blockIdx.x * 256 + threadIdx.x) >> 6;
        int lane = threadIdx.x & 63;
        const float4* rp = (const float4*)(x + (size_t)row * DIM);
        float4 v[3];
        float ss = 0.f;
#pragma unroll
        for (int i = 0; i < 3; ++i) {
            v[i] = rp[lane + i * 64];
            ss += v[i].x * v[i].x + v[i].y * v[i].y + v[i].z * v[i].z + v[i].w * v[i].w;
        }
        ss = wave_sum(ss);
        float sc = 1.0f / fmaxf(sqrtf(ss), NORM_EPS_);
        _Float16* op = x16 + (size_t)row * DIM;
#pragma unroll
        for (int i = 0; i < 3; ++i) {
            f16x4 h;
            h[0] = (_Float16)(v[i].x * sc); h[1] = (_Float16)(v[i].y * sc);
            h[2] = (_Float16)(v[i].z * sc); h[3] = (_Float16)(v[i].w * sc);
            *(f16x4*)(op + 4 * (lane + i * 64)) = h;
        }
    } else {
        int i = (blockIdx.x - XBLOCKS) * 256 + threadIdx.x;
        const float4 a = *(const float4*)(w + (size_t)i * 8);
        const float4 b = *(const float4*)(w + (size_t)i * 8 + 4);
        f16x8 h;
        h[0] = (_Float16)a.x; h[1] = (_Float16)a.y; h[2] = (_Float16)a.z; h[3] = (_Float16)a.w;
        h[4] = (_Float16)b.x; h[5] = (_Float16)b.y; h[6] = (_Float16)b.z; h[7] = (_Float16)b.w;
        *(f16x8*)(w16 + (size_t)i * 8) = h;
    }
}

// ---------------------------------------------------------------- row norms (tier 2/3)
__global__ __launch_bounds__(256) void rownorm_kernel(
    const float* __restrict__ x, float* __restrict__ invn)
{
    int wave = (blockIdx.x * 256 + threadIdx.x) >> 6;
    int lane = threadIdx.x & 63;
    const float4* row = (const float4*)(x + (size_t)wave * DIM);
    float s = 0.f;
#pragma unroll
    for (int i = 0; i < 3; ++i) {
        float4 v = row[lane + i * 64];
        s += v.x * v.x + v.y * v.y + v.z * v.z + v.w * v.w;
    }
    s = wave_sum(s);
    if (lane == 0) invn[wave] = 1.0f / fmaxf(sqrtf(s), NORM_EPS_);
}

// ================================================================ fast GEMM
// 256x256 tile, 8 waves (2M x 4N, per-wave 128x64). Phases over K-halves of
// 32: 24 phases, 4-slab LDS ring (128 KB), stage 2 slabs ahead, counted
// vmcnt(8) + ONE s_barrier per phase. T5: setprio(1) around MFMA cluster.
// Epilogue: full-line C stores (n-inner loop) + fused colpass1 partials.
// (r12 structure — measured best; r13's 2-slab/2-barrier variant regressed.)
#define GKH   32              // K per phase
#define NKH   (DIM / GKH)     // 24 phases

__global__ void __launch_bounds__(512, 1) gemm16(
    const _Float16* __restrict__ A,   // x16 [MROWS][DIM]
    const _Float16* __restrict__ B,   // w16 [NCLU][DIM]
    const float* __restrict__ bias,
    _Float16* __restrict__ out,
    float* __restrict__ colpart)      // [64 rowblocks][NCLU]
{
    __shared__ __align__(16) _Float16 AS[4][8192];  // 4 x 16 KB
    __shared__ __align__(16) _Float16 BS[4][8192];  // 4 x 16 KB

    const int tid  = threadIdx.x;
    const int lane = tid & 63;
    const int wid  = tid >> 6;          // 0..7
    const int wm   = wid >> 2;          // 0..1  (M)
    const int wn   = wid & 3;           // 0..3  (N)

    // bijective XCD-aware swizzle (nwg = 1024, %8 == 0)
    const int nwg = gridDim.x;
    const int cpx = nwg >> 3;
    const int swz = (blockIdx.x & 7) * cpx + (blockIdx.x >> 3);
    const int brow = (swz >> 4) * 256;   // 64 row-blocks
    const int bcol = (swz & 15) * 256;   // 16 col-blocks

    // ---- staging decode: LDS granule G (16B) holds (pairrow pr=G>>3, slot s=G&7)
    // with content row r = 2*pr + (s>>2), k-chunk q = (s&3) ^ (pr&3).
    const int G0 = tid, G1 = tid + 512;
    const int pr0 = G0 >> 3, s0 = G0 & 7;
    const int rr0 = pr0 * 2 + (s0 >> 2), qq0 = (s0 & 3) ^ (pr0 & 3);
    const int pr1 = G1 >> 3, s1 = G1 & 7;
    const int rr1 = pr1 * 2 + (s1 >> 2), qq1 = (s1 & 3) ^ (pr1 & 3);

    const _Float16* sA0 = A + (size_t)(brow + rr0) * DIM + qq0 * 8;
    const _Float16* sA1 = A + (size_t)(brow + rr1) * DIM + qq1 * 8;
    const _Float16* sB0 = B + (size_t)(bcol + rr0) * DIM + qq0 * 8;
    const _Float16* sB1 = B + (size_t)(bcol + rr1) * DIM + qq1 * 8;
    const int ldsOff0 = wid * 512;          // f16 units; lane adds 16B via HW
    const int ldsOff1 = wid * 512 + 4096;

    // ---- fragment read geometry (16x16x32: lane=(q,fr), k=q*8..+8)
    const int q  = lane >> 4;
    const int fr = lane & 15;
    const int qp = q ^ ((fr >> 1) & 3);                    // XOR involution
    const int fbase = ((fr & 1) * 4 + qp) * 8;
    const int abase = (wm * 64 + (fr >> 1)) * 64 + fbase;  // m stride: 512
    const int bbase = (wn * 32 + (fr >> 1)) * 64 + fbase;  // n stride: 512

    f32x4 acc[8][4] = {};

#define STAGE4(slot, kh) {                                  \
    const int ko_ = (kh) * GKH;                             \
    gl_lds16(sA0 + ko_, &AS[slot][ldsOff0]);                \
    gl_lds16(sA1 + ko_, &AS[slot][ldsOff1]);                \
    gl_lds16(sB0 + ko_, &BS[slot][ldsOff0]);                \
    gl_lds16(sB1 + ko_, &BS[slot][ldsOff1]); }

#define PHASE(slotC, slotS, khS) {                                         \
    STAGE4(slotS, khS);                                                    \
    asm volatile("s_waitcnt vmcnt(8)" ::: "memory");                       \
    __builtin_amdgcn_s_barrier();                                          \
    asm volatile("" ::: "memory");                                         \
    f16x8 af[8], bf[4];                                                    \
    _Pragma("unroll")                                                      \
    for (int m = 0; m < 8; ++m)                                            \
        af[m] = *(const f16x8*)&AS[slotC][abase + m * 512];                \
    _Pragma("unroll")                                                      \
    for (int n = 0; n < 4; ++n)                                            \
        bf[n] = *(const f16x8*)&BS[slotC][bbase + n * 512];                \
    __builtin_amdgcn_s_setprio(1);                                         \
    _Pragma("unroll")                                                      \
    for (int m = 0; m < 8; ++m)                                            \
        _Pragma("unroll")                                                  \
        for (int n = 0; n < 4; ++n)                                        \
            acc[m][n] = __builtin_amdgcn_mfma_f32_16x16x32_f16(            \
                af[m], bf[n], acc[m][n], 0, 0, 0);                         \
    __builtin_amdgcn_s_setprio(0); }

    // prologue: k-halves 0,1 into slots 0,1  (8 loads outstanding)
    STAGE4(0, 0);
    STAGE4(1, 1);

    for (int i6 = 0; i6 < 6; ++i6) {       // 6 x 4 = 24 phases
        const int i = i6 * 4;
        const int kh2 = i + 2;
        const int kh3 = i + 3;
        const int kh4 = (i + 4 < NKH) ? i + 4 : i + 4 - NKH;
        const int kh5 = (i + 5 < NKH) ? i + 5 : i + 5 - NKH;
        PHASE(0, 2, kh2);
        PHASE(1, 3, kh3);
        PHASE(2, 0, kh4);
        PHASE(3, 1, kh5);
    }
#undef PHASE
#undef STAGE4

    __syncthreads();                       // drain all loads; LDS reusable

    // epilogue: full-line C writes (n innermost: 4 stores fill one 128B line
    // per row-quadrant) + fused colpass1 partial sums.
    // C/D layout: col=lane&15, row=(lane>>4)*4+j
    float cs[4] = {0.f, 0.f, 0.f, 0.f};
    float bv[4];
#pragma unroll
    for (int n = 0; n < 4; ++n) bv[n] = bias[bcol + wn * 64 + n * 16 + fr];
#pragma unroll
    for (int m = 0; m < 8; ++m) {
        int row0 = brow + wm * 128 + m * 16 + (q << 2);
#pragma unroll
        for (int j = 0; j < 4; ++j) {
            size_t ro = (size_t)(row0 + j) * NCLU + bcol + wn * 64 + fr;
#pragma unroll
            for (int n = 0; n < 4; ++n) {
                float v = acc[m][n][j] + bv[n];
                out[ro + n * 16] = (_Float16)v;
                cs[n] += __expf(v * TT_INV - COL_SHIFT);
            }
        }
    }
    float cred_local[4];
#pragma unroll
    for (int n = 0; n < 4; ++n) {
        float c2 = cs[n];
        c2 += __shfl_xor(c2, 16);
        c2 += __shfl_xor(c2, 32);          // sum over q -> wave's 128 rows
        cred_local[n] = c2;
    }
    float* cred = (float*)&AS[0][0];       // [wm][wn][n][fr] = 512 f32
#pragma unroll
    for (int n = 0; n < 4; ++n)
        if (q == 0) cred[((wm * 4 + wn) * 4 + n) * 16 + fr] = cred_local[n];
    __syncthreads();
    if (tid < 256) {
        int wn2 = tid >> 6, n2 = (tid >> 4) & 3, fr2 = tid & 15;
        float S = cred[((0 * 4 + wn2) * 4 + n2) * 16 + fr2]
                + cred[((1 * 4 + wn2) * 4 + n2) * 16 + fr2];
        colpart[(size_t)(swz >> 4) * NCLU + bcol + wn2 * 64 + n2 * 16 + fr2] = S;
    }
}

// colfin1: a1[b,k] = -COL_SHIFT - ln( sum_rb colpart[b*4+rb][k] )   (exact, no eps)
__global__ __launch_bounds__(256) void colfin_kernel(
    const float* __restrict__ part, float* __restrict__ a1)
{
    int i = blockIdx.x * 256 + threadIdx.x;   // 65536
    int b = i >> 12, k = i & (NCLU - 1);
    const float* p = part + (size_t)(b * 4) * NCLU + k;
    float s = 0.f;
#pragma unroll
    for (int rb = 0; rb < 4; ++rb) { s += *p; p += NCLU; }
    a1[i] = -COL_SHIFT - __logf(s);
}

// ============================================ fused row+col Sinkhorn pass
// LDS-staged variant: 512 threads; phase 1 stages the 16x4096 f16 chunk into
// LDS while computing row sums; phase 2 reads LDS instead of re-reading global.
template <bool FIRST>
__global__ void __launch_bounds__(512, 1) rcpassL_kernel(
    const _Float16* __restrict__ L, const float* __restrict__ a_in,
    const float* __restrict__ b_in, float* __restrict__ b_out,
    float* __restrict__ part)         // [1024][NCLU]
{
    __shared__ __align__(16) _Float16 Lsh[16][NCLU];   // 128 KB
    __shared__ float wgt_sh[16];
    const int tid  = threadIdx.x;          // 0..511
    const int lane = tid & 63;
    const int wv   = tid >> 6;             // 0..7
    const int chunk = blockIdx.x;          // 0..1023
    const int b     = chunk >> 6;          // batch
    const int row0  = chunk * 16;
    const float* av = a_in + (size_t)b * NCLU;

    float ar[8][8];
#pragma unroll
    for (int i = 0; i < 8; ++i) {
        int c = i * 64 + lane;
        *(float4*)&ar[i][0] = *(const float4*)&av[c * 8];
        *(float4*)&ar[i][4] = *(const float4*)&av[c * 8 + 4];
    }

#pragma unroll
    for (int rr = 0; rr < 2; ++rr) {
        int lr  = wv * 2 + rr;
        int row = row0 + lr;
        const _Float16* Lr = L + (size_t)row * NCLU;
        float bp = FIRST ? 0.f : b_in[row];
        float s = 0.f;
#pragma unroll
        for (int i = 0; i < 8; ++i) {
            int c = i * 64 + lane;
            f16x8 h = *(const f16x8*)&Lr[c * 8];
            *(f16x8*)&Lsh[lr][c * 8] = h;
#pragma unroll
            for (int j = 0; j < 8; ++j)
                s += __expf((float)h[j] * TT_INV + ar[i][j] + bp);
        }
        s = wave_sum(s);
        if (lane == 0) {
            float bn = bp - __logf(s + SK_EPS_);
            b_out[row] = bn;
            wgt_sh[lr] = __expf(bn);
        }
    }
    __syncthreads();

    float aown[8];
    *(float4*)&aown[0] = *(const float4*)&av[tid * 8];
    *(float4*)&aown[4] = *(const float4*)&av[tid * 8 + 4];
    float acc[8] = {};
    for (int rr = 0; rr < 16; ++rr) {
        f16x8 h = *(const f16x8*)&Lsh[rr][tid * 8];
        float wg = wgt_sh[rr];
#pragma unroll
        for (int j = 0; j < 8; ++j)
            acc[j] += __expf((float)h[j] * TT_INV + aown[j]) * wg;
    }
    float* P = part + (size_t)chunk * NCLU;
    f32x4 w0, w1;
    w0[0] = acc[0]; w0[1] = acc[1]; w0[2] = acc[2]; w0[3] = acc[3];
    w1[0] = acc[4]; w1[1] = acc[5]; w1[2] = acc[6]; w1[3] = acc[7];
    *(f32x4*)&P[tid * 8]     = w0;
    *(f32x4*)&P[tid * 8 + 4] = w1;
}

// colfinN: a_out[b,k] = a_in[b,k] - ln( sum_{c in batch's 64 chunks} part[c][k] + eps )
__global__ __launch_bounds__(256) void colfinN_kernel(
    const float* __restrict__ part, const float* __restrict__ a_in,
    float* __restrict__ a_out)
{
    int i = blockIdx.x * 256 + threadIdx.x;   // 65536
    int b = i >> 12, k = i & (NCLU - 1);
    const float* p = part + (size_t)(b * 64) * NCLU + k;
    float s = 0.f;
#pragma unroll 8
    for (int c = 0; c < 64; ++c) { s += *p; p += NCLU; }
    a_out[i] = a_in[i] - __logf(s + SK_EPS_);
}

// ------------------------------------------------- tier-2/3 GEMM (convert in-kernel)
#define BM 128
#define BN 128
#define BKF 32
#define LDK 40

__device__ __forceinline__ f16x8 pack8(float4 lo, float4 hi, float sc) {
    f16x8 h;
    h[0] = (_Float16)(lo.x * sc); h[1] = (_Float16)(lo.y * sc);
    h[2] = (_Float16)(lo.z * sc); h[3] = (_Float16)(lo.w * sc);
    h[4] = (_Float16)(hi.x * sc); h[5] = (_Float16)(hi.y * sc);
    h[6] = (_Float16)(hi.z * sc); h[7] = (_Float16)(hi.w * sc);
    return h;
}

template <typename OT>
__global__ __launch_bounds__(256) void gemm_f16(
    const float* __restrict__ x, const float* __restrict__ w,
    const float* __restrict__ bias, const float* __restrict__ invn,
    OT* __restrict__ out)
{
    __shared__ __align__(16) _Float16 As[BM * LDK];
    __shared__ __align__(16) _Float16 Bs[BN * LDK];

    const int tid  = threadIdx.x;
    const int lane = tid & 63;
    const int wid  = tid >> 6;
    const int wr = wid >> 1, wc = wid & 1;
    const int brow = blockIdx.y * BM;
    const int bcol = blockIdx.x * BN;

    const int r0 = tid >> 2;
    const int r1 = r0 + 64;
    const int kc = (tid & 3) * 8;
    const float sA0 = invn[brow + r0];
    const float sA1 = invn[brow + r1];
    const float* gA0 = x + (size_t)(brow + r0) * DIM + kc;
    const float* gA1 = x + (size_t)(brow + r1) * DIM + kc;
    const float* gB0 = w + (size_t)(bcol + r0) * DIM + kc;
    const float* gB1 = w + (size_t)(bcol + r1) * DIM + kc;

    f32x4 acc[4][4] = {};
    float4 a00, a01, a10, a11, b00, b01, b10, b11;
    a00 = *(const float4*)(gA0);     a01 = *(const float4*)(gA0 + 4);
    a10 = *(const float4*)(gA1);     a11 = *(const float4*)(gA1 + 4);
    b00 = *(const float4*)(gB0);     b01 = *(const float4*)(gB0 + 4);
    b10 = *(const float4*)(gB1);     b11 = *(const float4*)(gB1 + 4);

    const int NT = DIM / BKF;
    for (int kt = 0; kt < NT; ++kt) {
        __syncthreads();
        *(f16x8*)&As[r0 * LDK + kc] = pack8(a00, a01, sA0);
        *(f16x8*)&As[r1 * LDK + kc] = pack8(a10, a11, sA1);
        *(f16x8*)&Bs[r0 * LDK + kc] = pack8(b00, b01, 1.0f);
        *(f16x8*)&Bs[r1 * LDK + kc] = pack8(b10, b11, 1.0f);
        __syncthreads();

        if (kt + 1 < NT) {
            int k0 = (kt + 1) * BKF;
            a00 = *(const float4*)(gA0 + k0); a01 = *(const float4*)(gA0 + k0 + 4);
            a10 = *(const float4*)(gA1 + k0); a11 = *(const float4*)(gA1 + k0 + 4);
            b00 = *(const float4*)(gB0 + k0); b01 = *(const float4*)(gB0 + k0 + 4);
            b10 = *(const float4*)(gB1 + k0); b11 = *(const float4*)(gB1 + k0 + 4);
        }

        const int ko = (lane >> 4) * 8;
        f16x8 af[4], bf[4];
#pragma unroll
        for (int m = 0; m < 4; ++m)
            af[m] = *(const f16x8*)&As[(wr * 64 + m * 16 + (lane & 15)) * LDK + ko];
#pragma unroll
        for (int n = 0; n < 4; ++n)
            bf[n] = *(const f16x8*)&Bs[(wc * 64 + n * 16 + (lane & 15)) * LDK + ko];
#pragma unroll
        for (int m = 0; m < 4; ++m)
#pragma unroll
            for (int n = 0; n < 4; ++n)
                acc[m][n] = __builtin_amdgcn_mfma_f32_16x16x32_f16(
                    af[m], bf[n], acc[m][n], 0, 0, 0);
    }

#pragma unroll
    for (int n = 0; n < 4; ++n) {
        int col = bcol + wc * 64 + n * 16 + (lane & 15);
        float bv = bias[col];
#pragma unroll
        for (int m = 0; m < 4; ++m) {
            int row0 = brow + wr * 64 + m * 16 + ((lane >> 4) << 2);
#pragma unroll
            for (int j = 0; j < 4; ++j)
                out[(size_t)(row0 + j) * NCLU + col] = (OT)(acc[m][n][j] + bv);
        }
    }
}

// ------------------------------------------------------------ column passes (tier 2/3)
template <typename T>
__global__ __launch_bounds__(256) void colpass_kernel(
    const T* __restrict__ L, const float* __restrict__ a_in,
    const float* __restrict__ b_in, float* __restrict__ a_out)
{
    __shared__ float bsh[NTOK];
    __shared__ float ss[4][64];
    int b = blockIdx.x >> 6;
    int k = ((blockIdx.x & 63) << 6) + (threadIdx.x & 63);
    int wv = threadIdx.x >> 6;
    int lane = threadIdx.x & 63;
    const bool first = (b_in == nullptr);
    if (first) {
        for (int i = threadIdx.x; i < NTOK; i += 256) bsh[i] = 0.f;
    } else {
        for (int i = threadIdx.x; i < NTOK; i += 256) bsh[i] = b_in[b * NTOK + i];
    }
    __syncthreads();
    float aval = first ? -COL_SHIFT : a_in[b * NCLU + k];
    const T* p = L + (size_t)b * NTOK * NCLU + (size_t)(wv * 256) * NCLU + k;
    float s = 0.f;
#pragma unroll 4
    for (int n = 0; n < 256; ++n) {
        s += __expf((float)(*p) * TT_INV + aval + bsh[wv * 256 + n]);
        p += NCLU;
    }
    ss[wv][lane] = s;
    __syncthreads();
    if (wv == 0) {
        float S = ss[0][lane] + ss[1][lane] + ss[2][lane] + ss[3][lane];
        a_out[b * NCLU + k] = aval - __logf(first ? S : S + SK_EPS_);
    }
}

template <typename T>
__global__ __launch_bounds__(256) void colpassV_kernel(
    const T* __restrict__ L, const float* __restrict__ a_in,
    const float* __restrict__ b_in, float* __restrict__ a_out)
{
    __shared__ float bsh[NTOK];
    __shared__ float red[16][16][8];   // 8 KB
    const int b     = blockIdx.x >> 5;
    const int strip = blockIdx.x & 31;
    const int cc    = threadIdx.x & 15;
    const int rg    = threadIdx.x >> 4;
    const int col0  = strip * 128 + cc * 8;
    for (int i = threadIdx.x; i < NTOK; i += 256) bsh[i] = b_in[b * NTOK + i];
    __syncthreads();
    const float4 av0 = *(const float4*)(a_in + b * NCLU + col0);
    const float4 av1 = *(const float4*)(a_in + b * NCLU + col0 + 4);
    const float av[8] = {av0.x, av0.y, av0.z, av0.w, av1.x, av1.y, av1.z, av1.w};
    float s[8] = {};
    const T* p = L + (size_t)b * NTOK * NCLU + (size_t)rg * NCLU + col0;
    for (int it = 0; it < 64; ++it) {
        F8 Lv = load8(p);
        float bpv = bsh[it * 16 + rg];
#pragma unroll
        for (int j = 0; j < 8; ++j) s[j] += __expf(Lv.v[j] * TT_INV + av[j] + bpv);
        p += (size_t)16 * NCLU;
    }
#pragma unroll
    for (int j = 0; j < 8; ++j) red[rg][cc][j] = s[j];
    __syncthreads();
    if (threadIdx.x < 128) {
        int c2 = threadIdx.x >> 3, j2 = threadIdx.x & 7;
        float S = 0.f;
#pragma unroll
        for (int g = 0; g < 16; ++g) S += red[g][c2][j2];
        int col = strip * 128 + c2 * 8 + j2;
        a_out[b * NCLU + col] = a_in[b * NCLU + col] - __logf(S + SK_EPS_);
    }
}

// ------------------------------------------------------------- row passes (tier 2/3)
template <typename T>
__global__ __launch_bounds__(256) void rowpass_kernel(
    const T* __restrict__ L, const float* __restrict__ a_in,
    const float* __restrict__ b_in, float* __restrict__ b_out)
{
    int row  = (blockIdx.x * 256 + threadIdx.x) >> 6;
    int lane = threadIdx.x & 63;
    int b = row >> 10;
    const T* Lr = L + (size_t)row * NCLU;
    const float* av = a_in + (size_t)b * NCLU;
    float bp = b_in ? b_in[row] : 0.f;
    float s = 0.f;
#pragma unroll
    for (int i = 0; i < 8; ++i) {
        int c = i * 64 + lane;
        F8 Lv = load8(Lr + c * 8);
        F8 Av = load8(av + c * 8);
#pragma unroll
        for (int j = 0; j < 8; ++j)
            s += __expf(Lv.v[j] * TT_INV + Av.v[j] + bp);
    }
    s = wave_sum(s);
    if (lane == 0) b_out[row] = bp - __logf(s + SK_EPS_);
}

// ---------------- final: assignments + per-row loss (single pass over L)
template <typename T>
__global__ __launch_bounds__(256) void final_kernel(
    const T* __restrict__ L, const float* __restrict__ a3,
    const float* __restrict__ b2, float* __restrict__ out,
    float* __restrict__ rowloss)
{
    __shared__ float red[3][4];
    const int row  = blockIdx.x;
    const int tid  = threadIdx.x;
    const int lane = tid & 63;
    const int wv   = tid >> 6;
    const int b    = row >> 10;
    const T* Lr = L + (size_t)row * NCLU;
    const float* av = a3 + (size_t)b * NCLU;
    const float bp = b2[row];

    float e[2][8];
    float rs = 0.f, q = 0.f, sP = 0.f;
#pragma unroll
    for (int jj = 0; jj < 2; ++jj) {
        int c = tid + jj * 256;
        F8 Lv = load8(Lr + c * 8);
        F8 Av = load8(av + c * 8);
#pragma unroll
        for (int j = 0; j < 8; ++j) {
            float P  = Lv.v[j] * PT_INV;
            float ev = __expf(Lv.v[j] * TT_INV + Av.v[j] + bp);
            e[jj][j] = ev;
            rs += ev;
            q  += ev * P;
            sP += __expf(P - P_SHIFT);
        }
    }
    rs = wave_sum(rs); q = wave_sum(q); sP = wave_sum(sP);
    if (lane == 0) { red[0][wv] = rs; red[1][wv] = q; red[2][wv] = sP; }
    __syncthreads();
    rs = red[0][0] + red[0][1] + red[0][2] + red[0][3];
    q  = red[1][0] + red[1][1] + red[1][2] + red[1][3];
    sP = red[2][0] + red[2][1] + red[2][2] + red[2][3];

    const float inv = 1.0f / (rs + SK_EPS_);
    const float lse = P_SHIFT + __logf(sP);

    float* Or = out + (size_t)row * NCLU;
#pragma unroll
    for (int jj = 0; jj < 2; ++jj) {
        int c = tid + jj * 256;
        f32x4 w0, w1;
        w0[0] = e[jj][0] * inv; w0[1] = e[jj][1] * inv;
        w0[2] = e[jj][2] * inv; w0[3] = e[jj][3] * inv;
        w1[0] = e[jj][4] * inv; w1[1] = e[jj][5] * inv;
        w1[2] = e[jj][6] * inv; w1[3] = e[jj][7] * inv;
        __builtin_nontemporal_store(w0, (f32x4*)(Or + c * 8));
        __builtin_nontemporal_store(w1, (f32x4*)(Or + c * 8 + 4));
    }
    if (tid == 0) rowloss[row] = q * inv - lse * (rs * inv);
}

// ------------------------------------------------------------- loss reduce
__global__ __launch_bounds__(256) void lossred_kernel(
    const float* __restrict__ rowloss, float* __restrict__ out_loss)
{
    __shared__ float red[4];
    int tid = threadIdx.x, lane = tid & 63, wv = tid >> 6;
    float s = 0.f;
    for (int i = tid; i < MROWS; i += 256) s += rowloss[i];
    s = wave_sum(s);
    if (lane == 0) red[wv] = s;
    __syncthreads();
    if (tid == 0)
        out_loss[0] = -(red[0] + red[1] + red[2] + red[3]) / (float)MROWS;
}

// ------------------------------------------------------------------ launch
extern "C" void kernel_launch(void* const* d_in, const int* in_sizes, int n_in,
                              void* d_out, int out_size, void* d_ws, size_t ws_size,
                              hipStream_t stream)
{
    const float* x    = (const float*)d_in[0];
    const float* w    = (const float*)d_in[1];
    const float* bias = (const float*)d_in[2];
    float* out = (float*)d_out;
    char* base = (char*)d_ws;
    float* ws  = (float*)d_ws;   // small region: a1..a3, b1, b2, rowloss (<1 MiB)

    float* a1      = ws;
    float* a2      = a1 + BATCH * NCLU;
    float* a3      = a2 + BATCH * NCLU;
    float* b1      = a3 + BATCH * NCLU;
    float* b2      = b1 + MROWS;
    float* rowloss = b2 + MROWS;

    const size_t SMALL = 1u << 20;
    const size_t L16B  = (size_t)MROWS * NCLU * 2;   // 128 MiB
    const size_t X16B  = (size_t)MROWS * DIM * 2;    // 24 MiB
    const size_t W16B  = (size_t)NCLU * DIM * 2;     // 6 MiB
    const size_t PARTB = (size_t)64 * NCLU * 4;      // 1 MiB

    const int CB = BATCH * (NCLU / 64);  // 1024
    const int RB = MROWS / 4;            // 4096

    if (ws_size >= SMALL + L16B + X16B + W16B + PARTB) {
        // tier 1: merged precast + 256^2 phase-pipelined GEMM + fused passes
        _Float16* L16 = (_Float16*)(base + SMALL);
        _Float16* X16 = (_Float16*)(base + SMALL + L16B);
        _Float16* W16 = (_Float16*)(base + SMALL + L16B + X16B);
        float*    part1 = (float*)(base + SMALL + L16B + X16B + W16B);
        // part (16 MiB) overlays X16 (24 MiB): X16 is dead after gemm16.
        float*    part  = (float*)(base + SMALL + L16B);

        castxw_kernel<<<XBLOCKS + WBLOCKS, 256, 0, stream>>>(x, w, X16, W16);
        gemm16<<<(MROWS / 256) * (NCLU / 256), 512, 0, stream>>>(X16, W16, bias, L16, part1);
        colfin_kernel<<<BATCH * NCLU / 256, 256, 0, stream>>>(part1, a1);
        rcpassL_kernel<true ><<<MROWS / 16, 512, 0, stream>>>(L16, a1, nullptr, b1, part);
        colfinN_kernel<<<BATCH * NCLU / 256, 256, 0, stream>>>(part, a1, a2);
        rcpassL_kernel<false><<<MROWS / 16, 512, 0, stream>>>(L16, a2, b1, b2, part);
        colfinN_kernel<<<BATCH * NCLU / 256, 256, 0, stream>>>(part, a2, a3);
        final_kernel<_Float16><<<MROWS, 256, 0, stream>>>(L16, a3, b2, out, rowloss);
        lossred_kernel<<<1, 256, 0, stream>>>(rowloss, out + (size_t)MROWS * NCLU);
    } else if (ws_size >= SMALL + L16B) {
        // tier 2: fp16 logits in ws, convert inside GEMM
        float* invn = rowloss + MROWS;
        _Float16* L16 = (_Float16*)(base + SMALL);
        rownorm_kernel<<<MROWS / 4, 256, 0, stream>>>(x, invn);
        dim3 gg(NCLU / BN, MROWS / BM);
        gemm_f16<_Float16><<<gg, 256, 0, stream>>>(x, w, bias, invn, L16);
        colpass_kernel<_Float16><<<CB, 256, 0, stream>>>(L16, nullptr, nullptr, a1);
        rowpass_kernel<_Float16><<<RB, 256, 0, stream>>>(L16, a1, nullptr, b1);
        colpassV_kernel<_Float16><<<BATCH * 32, 256, 0, stream>>>(L16, a1, b1, a2);
        rowpass_kernel<_Float16><<<RB, 256, 0, stream>>>(L16, a2, b1, b2);
        colpassV_kernel<_Float16><<<BATCH * 32, 256, 0, stream>>>(L16, a2, b2, a3);
        final_kernel<_Float16><<<MROWS, 256, 0, stream>>>(L16, a3, b2, out, rowloss);
        lossred_kernel<<<1, 256, 0, stream>>>(rowloss, out + (size_t)MROWS * NCLU);
    } else {
        // tier 3: f32 logits in d_out
        float* invn = rowloss + MROWS;
        rownorm_kernel<<<MROWS / 4, 256, 0, stream>>>(x, invn);
        dim3 gg(NCLU / BN, MROWS / BM);
        gemm_f16<float><<<gg, 256, 0, stream>>>(x, w, bias, invn, out);
        colpass_kernel<float><<<CB, 256, 0, stream>>>(out, nullptr, nullptr, a1);
        rowpass_kernel<float><<<RB, 256, 0, stream>>>(out, a1, nullptr, b1);
        colpassV_kernel<float><<<BATCH * 32, 256, 0, stream>>>(out, a1, b1, a2);
        rowpass_kernel<float><<<RB, 256, 0, stream>>>(out, a2, b1, b2);
        colpassV_kernel<float><<<BATCH * 32, 256, 0, stream>>>(out, a2, b2, a3);
        final_kernel<float><<<MROWS, 256, 0, stream>>>(out, a3, b2, out, rowloss);
        lossred_kernel<<<1, 256, 0, stream>>>(rowloss, out + (size_t)MROWS * NCLU);
    }
}